// Round 2
// baseline (563.467 us; speedup 1.0000x reference)
//
#include <hip/hip_runtime.h>

// Problem constants
#define NB 8
#define NNODE 2048
#define NEDGE 65536
#define NR 6
#define H 128
// M = NB*NEDGE = 524288 rows; each block handles 64 rows.
#define BM 64

__device__ __forceinline__ float silu_fast(float a) {
    return a / (1.0f + __expf(-a));
}
__device__ __forceinline__ float silu_acc(float a) {
    return a / (1.0f + expf(-a));
}

// ws layout (floats): u1[128] | u2[128] | v[128] | w3t[128*128] (c-major: w3t[c*128+o])
__global__ __launch_bounds__(128) void precomp_kernel(
    const float* __restrict__ emb_w,  // [128] (H x 1)
    const float* __restrict__ emb_b,  // [128]
    const float* __restrict__ lin_w,  // [128][384]
    const float* __restrict__ lin_b,  // [128]
    float* __restrict__ ws)
{
    const int o = threadIdx.x;  // 0..127
    const float* wrow = lin_w + o * 384;
    float u1 = 0.f, u2 = 0.f, v = lin_b[o];
    #pragma unroll 8
    for (int c = 0; c < 128; ++c) {
        float w1 = wrow[c];
        float w2 = wrow[128 + c];
        float ew = emb_w[c];
        float eb = emb_b[c];
        u1 += ew * w1;
        u2 += ew * w2;
        v  += eb * (w1 + w2);
    }
    ws[o]       = u1;
    ws[128 + o] = u2;
    ws[256 + o] = v;
    float* w3t = ws + 384;
    // transpose W3 (cols 256..383) into c-major
    #pragma unroll 8
    for (int c = 0; c < 128; ++c) {
        w3t[c * 128 + o] = wrow[256 + c];
    }
}

__global__ __launch_bounds__(256) void edge_kernel(
    const float* __restrict__ x,      // [8*2048]
    const float* __restrict__ rbf,    // [M*6]
    const int*   __restrict__ gi,     // [65536]
    const int*   __restrict__ gj,     // [65536]
    const float* __restrict__ rbf_w,  // [128*6]
    const float* __restrict__ rbf_b,  // [128]
    const float* __restrict__ ws,     // u1,u2,v,w3t
    float* __restrict__ out)          // [M*128]
{
    __shared__ float rT[H][BM];       // 32 KB : r transposed (c-major)
    __shared__ float wbuf[32 * H];    // 16 KB : one 32-c chunk of W3T

    const int tid = threadIdx.x;
    const long m0 = (long)blockIdx.x * BM;
    const float* w3t = ws + 384;

    // ---------------- Phase A: r = silu(rbf @ rbf_w.T + rbf_b), transposed into LDS
    {
        const int el = tid & 63;          // local row
        const int c0 = (tid >> 6) * 32;   // this thread's 32 channels
        const long m = m0 + el;
        const float* rp = rbf + m * 6;
        const float rb0 = rp[0], rb1 = rp[1], rb2 = rp[2];
        const float rb3 = rp[3], rb4 = rp[4], rb5 = rp[5];
        #pragma unroll 4
        for (int cc = 0; cc < 32; ++cc) {
            const int c = c0 + cc;
            const float* wp = rbf_w + c * 6;
            float a = rbf_b[c];
            a += rb0 * wp[0];
            a += rb1 * wp[1];
            a += rb2 * wp[2];
            a += rb3 * wp[3];
            a += rb4 * wp[4];
            a += rb5 * wp[5];
            rT[c][el] = silu_fast(a);
        }
    }

    // ---------------- stage W3T chunk 0 into wbuf
    {
        #pragma unroll
        for (int ii = 0; ii < 4; ++ii) {
            const int f = ii * 256 + tid;           // float4 index within 16KB chunk
            ((float4*)wbuf)[f] = ((const float4*)w3t)[f];
        }
    }
    __syncthreads();

    // ---------------- Phase B: out_tile[64][128] += rT^T @ W3T  (fp32 register tiling)
    const int tx = tid & 31;   // 32 col-groups
    const int ty = tid >> 5;   // 8 row-groups
    const int oc = tx * 4;     // 4 output cols per thread
    const int er = ty * 8;     // 8 rows per thread

    float acc[8][4];
    #pragma unroll
    for (int a = 0; a < 8; ++a)
        #pragma unroll
        for (int b = 0; b < 4; ++b) acc[a][b] = 0.f;

    float4 pre0, pre1, pre2, pre3;
    for (int k = 0; k < 4; ++k) {
        // prefetch next chunk to registers while computing this one
        if (k < 3) {
            const float4* src = (const float4*)(w3t + (k + 1) * 32 * H);
            pre0 = src[0 * 256 + tid];
            pre1 = src[1 * 256 + tid];
            pre2 = src[2 * 256 + tid];
            pre3 = src[3 * 256 + tid];
        }
        #pragma unroll 8
        for (int cc = 0; cc < 32; ++cc) {
            const float4 w  = *(const float4*)&wbuf[cc * H + oc];
            const float4 ra = *(const float4*)&rT[k * 32 + cc][er];
            const float4 rb = *(const float4*)&rT[k * 32 + cc][er + 4];
            const float rr[8] = {ra.x, ra.y, ra.z, ra.w, rb.x, rb.y, rb.z, rb.w};
            const float wv[4] = {w.x, w.y, w.z, w.w};
            #pragma unroll
            for (int a = 0; a < 8; ++a)
                #pragma unroll
                for (int b = 0; b < 4; ++b)
                    acc[a][b] += rr[a] * wv[b];
        }
        if (k < 3) {
            __syncthreads();   // everyone done reading wbuf
            ((float4*)wbuf)[0 * 256 + tid] = pre0;
            ((float4*)wbuf)[1 * 256 + tid] = pre1;
            ((float4*)wbuf)[2 * 256 + tid] = pre2;
            ((float4*)wbuf)[3 * 256 + tid] = pre3;
            __syncthreads();   // new chunk visible
        }
    }

    // ---------------- Epilogue: rank-1 terms + bias + silu + store
    const float4 U1 = *(const float4*)(ws + oc);
    const float4 U2 = *(const float4*)(ws + 128 + oc);
    const float4 V  = *(const float4*)(ws + 256 + oc);
    const int b = (int)(m0 >> 16);              // E = 65536 = 2^16
    const float* xb = x + b * NNODE;

    #pragma unroll
    for (int a = 0; a < 8; ++a) {
        const long m = m0 + er + a;
        const int e = (int)(m & (NEDGE - 1));
        const float s = xb[gi[e]];
        const float t = xb[gj[e]];
        float4 o4;
        o4.x = silu_acc(acc[a][0] + s * U1.x + t * U2.x + V.x);
        o4.y = silu_acc(acc[a][1] + s * U1.y + t * U2.y + V.y);
        o4.z = silu_acc(acc[a][2] + s * U1.z + t * U2.z + V.z);
        o4.w = silu_acc(acc[a][3] + s * U1.w + t * U2.w + V.w);
        *(float4*)(out + m * H + oc) = o4;
    }
}

extern "C" void kernel_launch(void* const* d_in, const int* in_sizes, int n_in,
                              void* d_out, int out_size, void* d_ws, size_t ws_size,
                              hipStream_t stream) {
    const float* x     = (const float*)d_in[0];
    const float* rbf   = (const float*)d_in[1];
    const int*   gi    = (const int*)  d_in[2];
    const int*   gj    = (const int*)  d_in[3];
    const float* emb_w = (const float*)d_in[4];
    const float* emb_b = (const float*)d_in[5];
    const float* rbf_w = (const float*)d_in[6];
    const float* rbf_b = (const float*)d_in[7];
    const float* lin_w = (const float*)d_in[8];
    const float* lin_b = (const float*)d_in[9];
    float* out = (float*)d_out;
    float* ws  = (float*)d_ws;

    precomp_kernel<<<1, 128, 0, stream>>>(emb_w, emb_b, lin_w, lin_b, ws);

    const int nblocks = (NB * NEDGE) / BM;   // 8192
    edge_kernel<<<nblocks, 256, 0, stream>>>(x, rbf, gi, gj, rbf_w, rbf_b, ws, out);
}

// Round 4
// 361.491 us; speedup vs baseline: 1.5587x; 1.5587x over previous
//
#include <hip/hip_runtime.h>

#define NB 8
#define NNODE 2048
#define NEDGE 65536
#define H 128
#define BM 64
#define RSTRIDE 132   // u32 per row: 128 + 4 pad -> 528B = 33*16B (b128-aligned, bank-spread)

typedef __attribute__((ext_vector_type(8))) short bf16x8;
typedef __attribute__((ext_vector_type(4))) float f32x4;

union U8 { uint4 u4; bf16x8 s8; };

__device__ __forceinline__ unsigned f32_bf16_rne(float f) {
    unsigned u = __float_as_uint(f);
    return (u + 0x7FFFu + ((u >> 16) & 1u)) >> 16;
}
__device__ __forceinline__ float bf16_f32(unsigned h) {
    return __uint_as_float(h << 16);
}
__device__ __forceinline__ float silu_f(float a) {
    return a / (1.0f + __expf(-a));
}

// ws layout (floats): u1[128] | u2[128] | v[128] | w3 frags (8192 u32 = 32KB)
// frag f = ks*8+nt : lane holds B[k=ks*32+(l>>4)*8+j][col=nt*16+(l&15)], j=0..7,
// packed as 4 u32 (bf16 pairs), stored at w3f[f*256 + lane*4 .. +3]
__global__ __launch_bounds__(64) void precomp_kernel(
    const float* __restrict__ emb_w, const float* __restrict__ emb_b,
    const float* __restrict__ lin_w, const float* __restrict__ lin_b,
    float* __restrict__ ws)
{
    const int bid = blockIdx.x;
    const int t = threadIdx.x;
    if (bid < 32) {
        const int ks = bid >> 3, nt = bid & 7;
        const int g = t >> 4, c = t & 15;
        const int col = nt * 16 + c;
        const float* src = lin_w + col * 384 + 256;
        uint4 w;
        {
            int k0 = ks * 32 + g * 8;
            w.x = f32_bf16_rne(src[k0 + 0]) | (f32_bf16_rne(src[k0 + 1]) << 16);
            w.y = f32_bf16_rne(src[k0 + 2]) | (f32_bf16_rne(src[k0 + 3]) << 16);
            w.z = f32_bf16_rne(src[k0 + 4]) | (f32_bf16_rne(src[k0 + 5]) << 16);
            w.w = f32_bf16_rne(src[k0 + 6]) | (f32_bf16_rne(src[k0 + 7]) << 16);
        }
        unsigned* w3f = (unsigned*)(ws + 384);
        *(uint4*)(w3f + bid * 256 + t * 4) = w;
    } else {
        const int o = (bid - 32) * 64 + t;   // 0..127
        const float* wrow = lin_w + o * 384;
        float u1 = 0.f, u2 = 0.f, v = lin_b[o];
        #pragma unroll 8
        for (int c = 0; c < 128; ++c) {
            float w1 = wrow[c], w2 = wrow[128 + c];
            u1 += emb_w[c] * w1;
            u2 += emb_w[c] * w2;
            v  += emb_b[c] * (w1 + w2);
        }
        ws[o] = u1; ws[128 + o] = u2; ws[256 + o] = v;
    }
}

__global__ __launch_bounds__(256, 4) void edge_kernel(
    const float* __restrict__ x,      // [8*2048]
    const float* __restrict__ rbf,    // [M*6]
    const int*   __restrict__ gi,     // [65536]
    const int*   __restrict__ gj,     // [65536]
    const float* __restrict__ rbf_w,  // [128*6]
    const float* __restrict__ rbf_b,  // [128]
    const float* __restrict__ ws,
    float* __restrict__ out)          // [M*128]
{
    __shared__ unsigned RHL[BM * RSTRIDE];  // 33792 B : {bf16 lo<<16 | hi} of silu'd r
    __shared__ float rbf_s[BM * 6];         // 1536 B

    const int tid  = threadIdx.x;
    const int wid  = tid >> 6;
    const int lane = tid & 63;
    const int g    = lane >> 4;
    const int c15  = lane & 15;
    const long m0  = (long)blockIdx.x * BM;

    // stage rbf rows for this block (64 rows x 6 f32 = 96 float4)
    if (tid < 96)
        ((float4*)rbf_s)[tid] = ((const float4*)(rbf + m0 * 6))[tid];

    // phase-A weights: this lane's 8 cols (col = nt*16+c15), 6 w + bias each, in regs
    float wa[8][6], wb[8];
    #pragma unroll
    for (int nt = 0; nt < 8; ++nt) {
        const int col = nt * 16 + c15;
        const float2* wp = (const float2*)(rbf_w + col * 6);
        float2 p0 = wp[0], p1 = wp[1], p2 = wp[2];
        wa[nt][0] = p0.x; wa[nt][1] = p0.y;
        wa[nt][2] = p1.x; wa[nt][3] = p1.y;
        wa[nt][4] = p2.x; wa[nt][5] = p2.y;
        wb[nt] = rbf_b[col];
    }
    __syncthreads();

    // ---- Phase A: preact in C-layout (row = wid*16 + g*4 + r, col = nt*16 + c15), fp32 exact
    {
        float acc[8][4];
        #pragma unroll
        for (int nt = 0; nt < 8; ++nt)
            #pragma unroll
            for (int r = 0; r < 4; ++r) acc[nt][r] = wb[nt];

        #pragma unroll
        for (int r = 0; r < 4; ++r) {
            const int row = wid * 16 + g * 4 + r;
            const float* q = rbf_s + row * 6;
            const float q0 = q[0], q1 = q[1], q2 = q[2];
            const float q3 = q[3], q4 = q[4], q5 = q[5];
            #pragma unroll
            for (int nt = 0; nt < 8; ++nt) {
                float d = acc[nt][r];
                d += q0 * wa[nt][0]; d += q1 * wa[nt][1];
                d += q2 * wa[nt][2]; d += q3 * wa[nt][3];
                d += q4 * wa[nt][4]; d += q5 * wa[nt][5];
                acc[nt][r] = d;
            }
        }
        // silu + hi/lo split + packed write
        #pragma unroll
        for (int nt = 0; nt < 8; ++nt)
            #pragma unroll
            for (int r = 0; r < 4; ++r) {
                const int row = wid * 16 + g * 4 + r;
                float y = silu_f(acc[nt][r]);
                unsigned hi = f32_bf16_rne(y);
                unsigned lo = f32_bf16_rne(y - bf16_f32(hi));
                RHL[row * RSTRIDE + nt * 16 + c15] = hi | (lo << 16);
            }
    }
    __syncthreads();

    // ---- Phase B: out[16 x 128] per wave = (Rh + Rl) @ W3h via MFMA
    f32x4 acc4[8];
    #pragma unroll
    for (int nt = 0; nt < 8; ++nt) acc4[nt] = (f32x4){0.f, 0.f, 0.f, 0.f};

    const unsigned* w3f = (const unsigned*)(ws + 384);
    const int rrow = wid * 16 + c15;   // A-operand row for this lane

    #pragma unroll
    for (int ks = 0; ks < 4; ++ks) {
        const unsigned* base = &RHL[rrow * RSTRIDE + ks * 32 + g * 8];
        uint4 wlo = *(const uint4*)base;         // words k0..k3
        uint4 whi = *(const uint4*)(base + 4);   // words k4..k7
        U8 Ah, Al;
        Ah.u4.x = (wlo.x & 0xFFFFu) | (wlo.y << 16);
        Ah.u4.y = (wlo.z & 0xFFFFu) | (wlo.w << 16);
        Ah.u4.z = (whi.x & 0xFFFFu) | (whi.y << 16);
        Ah.u4.w = (whi.z & 0xFFFFu) | (whi.w << 16);
        Al.u4.x = (wlo.x >> 16) | (wlo.y & 0xFFFF0000u);
        Al.u4.y = (wlo.z >> 16) | (wlo.w & 0xFFFF0000u);
        Al.u4.z = (whi.x >> 16) | (whi.y & 0xFFFF0000u);
        Al.u4.w = (whi.z >> 16) | (whi.w & 0xFFFF0000u);

        #pragma unroll
        for (int h = 0; h < 2; ++h) {
            U8 wf[4];
            #pragma unroll
            for (int q = 0; q < 4; ++q)
                wf[q].u4 = *(const uint4*)(w3f + ((ks * 8 + h * 4 + q) * 64 + lane) * 4);
            #pragma unroll
            for (int q = 0; q < 4; ++q) {
                const int nt = h * 4 + q;
                acc4[nt] = __builtin_amdgcn_mfma_f32_16x16x32_bf16(Ah.s8, wf[q].s8, acc4[nt], 0, 0, 0);
                acc4[nt] = __builtin_amdgcn_mfma_f32_16x16x32_bf16(Al.s8, wf[q].s8, acc4[nt], 0, 0, 0);
            }
        }
    }

    // ---- Epilogue: rank-1 + bias + silu + store (D-layout: row=g*4+r, col=nt*16+c15)
    const int b = blockIdx.x >> 10;              // 1024 blocks per batch
    const float* xb = x + b * NNODE;
    const int ebase = ((blockIdx.x & 1023) << 6) + wid * 16 + g * 4;

    float sr[4], tr[4];
    #pragma unroll
    for (int r = 0; r < 4; ++r) {
        const int e = ebase + r;
        sr[r] = xb[gi[e]];
        tr[r] = xb[gj[e]];
    }

    #pragma unroll
    for (int nt = 0; nt < 8; ++nt) {
        const int col = nt * 16 + c15;
        const float u1c = ws[col], u2c = ws[128 + col], vc = ws[256 + col];
        const long mbase = m0 + wid * 16 + g * 4;
        #pragma unroll
        for (int r = 0; r < 4; ++r) {
            float o = acc4[nt][r] + sr[r] * u1c + tr[r] * u2c + vc;
            out[(mbase + r) * H + col] = silu_f(o);
        }
    }
}

extern "C" void kernel_launch(void* const* d_in, const int* in_sizes, int n_in,
                              void* d_out, int out_size, void* d_ws, size_t ws_size,
                              hipStream_t stream) {
    const float* x     = (const float*)d_in[0];
    const float* rbf   = (const float*)d_in[1];
    const int*   gi    = (const int*)  d_in[2];
    const int*   gj    = (const int*)  d_in[3];
    const float* emb_w = (const float*)d_in[4];
    const float* emb_b = (const float*)d_in[5];
    const float* rbf_w = (const float*)d_in[6];
    const float* rbf_b = (const float*)d_in[7];
    const float* lin_w = (const float*)d_in[8];
    const float* lin_b = (const float*)d_in[9];
    float* out = (float*)d_out;
    float* ws  = (float*)d_ws;

    precomp_kernel<<<34, 64, 0, stream>>>(emb_w, emb_b, lin_w, lin_b, ws);

    const int nblocks = (NB * NEDGE) / BM;   // 8192
    edge_kernel<<<nblocks, 256, 0, stream>>>(x, rbf, gi, gj, rbf_w, rbf_b, ws, out);
}